// Round 1
// baseline (1563.068 us; speedup 1.0000x reference)
//
#include <hip/hip_runtime.h>
#include <stdint.h>

typedef unsigned short u16;
typedef __attribute__((ext_vector_type(8))) short s16x8;
typedef __attribute__((ext_vector_type(4))) float f32x4;

#define P_ 256
#define L_ 64
#define IDIM 512
#define H_ 1024
#define KTOT 1536

__device__ __forceinline__ u16 f2bf(float f) {
  union { float f; uint32_t u; } v; v.f = f;
  uint32_t u = v.u;
  return (u16)((u + 0x7FFFu + ((u >> 16) & 1u)) >> 16);
}
__device__ __forceinline__ float bf2f(u16 h) {
  union { uint32_t u; float f; } v; v.u = ((uint32_t)h) << 16;
  return v.f;
}
__device__ __forceinline__ float sigf(float x) { return 1.0f / (1.0f + __expf(-x)); }
__device__ __forceinline__ float tanh_fast(float x) {
  return 1.0f - 2.0f / (__expf(2.0f * x) + 1.0f);
}
__device__ __forceinline__ void async16(const u16* g, u16* l) {
  __builtin_amdgcn_global_load_lds(
      (__attribute__((address_space(1))) uint32_t*)g,
      (__attribute__((address_space(3))) uint32_t*)l, 16, 0, 0);
}

// ---- prep: W_cat_perm bf16 [4096][1536], rows n=4j+g <- orig r=g*1024+j ----
__global__ void prep_wcat(const float* __restrict__ Wih, const float* __restrict__ Whh,
                          const float* __restrict__ bih, const float* __restrict__ bhh,
                          u16* __restrict__ Wc, float* __restrict__ bp) {
  int n = blockIdx.x;
  int r = (n & 3) * H_ + (n >> 2);
  if (threadIdx.x == 0) bp[n] = bih[r] + bhh[r];
  const float* s1 = Wih + (size_t)r * IDIM;
  const float* s2 = Whh + (size_t)r * H_;
  u16* d = Wc + (size_t)n * KTOT;
  for (int k = threadIdx.x; k < KTOT; k += 256)
    d[k] = f2bf(k < IDIM ? s1[k] : s2[k - IDIM]);
}

// ---- prep: W_v (=W_in[2H:3H]) and W_out to bf16, b_v slice ----
__global__ void prep_wsmall(const float* __restrict__ Win, const float* __restrict__ bin,
                            const float* __restrict__ Wout,
                            u16* __restrict__ Wvb, u16* __restrict__ Wob, float* __restrict__ bv) {
  int j = blockIdx.x;
  if (threadIdx.x == 0) bv[j] = bin[2 * H_ + j];
  const float* sv = Win + (size_t)(2 * H_ + j) * H_;
  const float* so = Wout + (size_t)j * H_;
  for (int k = threadIdx.x; k < H_; k += 256) {
    Wvb[(size_t)j * H_ + k] = f2bf(sv[k]);
    Wob[(size_t)j * H_ + k] = f2bf(so[k]);
  }
}

// ---- gather embeddings -> X bf16 [t][p][i] ----
__global__ void gather_x(const int* __restrict__ paths, const float* __restrict__ emb,
                         u16* __restrict__ X) {
  int b = blockIdx.x;            // = p*64 + t (paths layout [P][L])
  int p = b >> 6, t = b & 63;
  int tok = paths[b];
  const float* src = emb + (size_t)tok * IDIM;
  u16* dst = X + ((size_t)t * P_ + p) * IDIM;
  int k = threadIdx.x * 4;
  float4 v = *(const float4*)(src + k);
  dst[k + 0] = f2bf(v.x); dst[k + 1] = f2bf(v.y);
  dst[k + 2] = f2bf(v.z); dst[k + 3] = f2bf(v.w);
}

// ---- fused LSTM step: gates GEMM [256x4096, K=1536] + gate nonlinearity ----
// grid (32,4): n0 = bx*128, p0 = by*64.  4 waves, wave tile 32x64.
__global__ void __launch_bounds__(256)
lstm_step(const u16* __restrict__ X, const u16* __restrict__ Hprev,
          u16* __restrict__ Hnext, float* __restrict__ Cs,
          const u16* __restrict__ Wc, const float* __restrict__ bp,
          const int* __restrict__ lengths, int t) {
  __shared__ __align__(16) u16 sA[64 * 64];    // [row][k] 128B rows, swizzled content
  __shared__ __align__(16) u16 sB[128 * 64];
  __shared__ float sG[64 * 128];
  const int tid = threadIdx.x;
  const int wid = tid >> 6, lane = tid & 63;
  const int p0 = blockIdx.y * 64;
  const int n0 = blockIdx.x * 128;
  const int m_base = (wid >> 1) * 32, n_base = (wid & 1) * 64;
  const int lrow = lane & 15, lgrp = lane >> 4;

  f32x4 acc[2][4];
#pragma unroll
  for (int a = 0; a < 2; ++a)
#pragma unroll
    for (int b = 0; b < 4; ++b)
#pragma unroll
      for (int e = 0; e < 4; ++e) acc[a][b][e] = 0.0f;

  for (int kk = 0; kk < 24; ++kk) {
    const int k0 = kk * 64;
    // stage A: 8 KB = 8 lds-blocks of 1KB (8 rows x 128B); 2 per wave
    {
      int ab = wid * 2;
#pragma unroll
      for (int i = 0; i < 2; ++i, ++ab) {
        int row = ab * 8 + (lane >> 3);
        int csrc = (lane & 7) ^ (row & 7);       // pre-swizzled source chunk
        int k = k0 + csrc * 8;
        const u16* src = (k0 < IDIM)
            ? X + ((size_t)t * P_ + p0 + row) * IDIM + k
            : Hprev + (size_t)(p0 + row) * H_ + (k - IDIM);
        async16(src, &sA[ab * 512]);
      }
    }
    // stage B: 16 KB = 16 blocks; 4 per wave
    {
      int bb = wid * 4;
#pragma unroll
      for (int i = 0; i < 4; ++i, ++bb) {
        int row = bb * 8 + (lane >> 3);
        int csrc = (lane & 7) ^ (row & 7);
        const u16* src = Wc + (size_t)(n0 + row) * KTOT + k0 + csrc * 8;
        async16(src, &sB[bb * 512]);
      }
    }
    __syncthreads();
#pragma unroll
    for (int ks = 0; ks < 2; ++ks) {
      const int q = ks * 4 + lgrp;               // 16B chunk index within row
      s16x8 fa[2], fb[4];
#pragma unroll
      for (int fm = 0; fm < 2; ++fm) {
        int r = m_base + fm * 16 + lrow;
        fa[fm] = *(const s16x8*)&sA[r * 64 + ((q ^ (r & 7)) * 8)];
      }
#pragma unroll
      for (int fn = 0; fn < 4; ++fn) {
        int r = n_base + fn * 16 + lrow;
        fb[fn] = *(const s16x8*)&sB[r * 64 + ((q ^ (r & 7)) * 8)];
      }
#pragma unroll
      for (int fm = 0; fm < 2; ++fm)
#pragma unroll
        for (int fn = 0; fn < 4; ++fn)
          acc[fm][fn] = __builtin_amdgcn_mfma_f32_16x16x32_bf16(fa[fm], fb[fn], acc[fm][fn], 0, 0, 0);
    }
    __syncthreads();
  }

  // epilogue: C/D map col=lane&15, row=(lane>>4)*4+reg  [verified m89]
#pragma unroll
  for (int fm = 0; fm < 2; ++fm)
#pragma unroll
    for (int fn = 0; fn < 4; ++fn)
#pragma unroll
      for (int r = 0; r < 4; ++r) {
        int row = m_base + fm * 16 + lgrp * 4 + r;
        int col = n_base + fn * 16 + lrow;
        sG[row * 128 + col] = acc[fm][fn][r];
      }
  __syncthreads();
  for (int idx = tid; idx < 64 * 32; idx += 256) {
    int pl = idx >> 5, jl = idx & 31;
    int p = p0 + pl, j = blockIdx.x * 32 + jl;
    const float* g = &sG[pl * 128 + jl * 4];
    const float* bb = &bp[n0 + jl * 4];
    float gi = g[0] + bb[0], gf = g[1] + bb[1], gg = g[2] + bb[2], go = g[3] + bb[3];
    size_t off = (size_t)p * H_ + j;
    if (t < lengths[p]) {
      float cn = sigf(gf) * Cs[off] + sigf(gi) * tanh_fast(gg);
      Cs[off] = cn;
      Hnext[off] = f2bf(sigf(go) * tanh_fast(cn));
    } else {
      Hnext[off] = Hprev[off];   // frozen: carry final h forward
    }
  }
}

// ---- tail GEMM: C[p][n] = sum_k A[p][k]*W[n][k] + bias[n] ; N=1024, K=1024 ----
__global__ void __launch_bounds__(256)
tail_gemm(const u16* __restrict__ A, const u16* __restrict__ W,
          const float* __restrict__ bias, u16* __restrict__ outB,
          float* __restrict__ outF, int bf16out) {
  __shared__ __align__(16) u16 sA[64 * 64];
  __shared__ __align__(16) u16 sB[128 * 64];
  const int tid = threadIdx.x;
  const int wid = tid >> 6, lane = tid & 63;
  const int p0 = blockIdx.y * 64;
  const int n0 = blockIdx.x * 128;
  const int m_base = (wid >> 1) * 32, n_base = (wid & 1) * 64;
  const int lrow = lane & 15, lgrp = lane >> 4;

  f32x4 acc[2][4];
#pragma unroll
  for (int a = 0; a < 2; ++a)
#pragma unroll
    for (int b = 0; b < 4; ++b)
#pragma unroll
      for (int e = 0; e < 4; ++e) acc[a][b][e] = 0.0f;

  for (int kk = 0; kk < 16; ++kk) {
    const int k0 = kk * 64;
    {
      int ab = wid * 2;
#pragma unroll
      for (int i = 0; i < 2; ++i, ++ab) {
        int row = ab * 8 + (lane >> 3);
        int csrc = (lane & 7) ^ (row & 7);
        async16(A + (size_t)(p0 + row) * H_ + k0 + csrc * 8, &sA[ab * 512]);
      }
    }
    {
      int bb = wid * 4;
#pragma unroll
      for (int i = 0; i < 4; ++i, ++bb) {
        int row = bb * 8 + (lane >> 3);
        int csrc = (lane & 7) ^ (row & 7);
        async16(W + (size_t)(n0 + row) * H_ + k0 + csrc * 8, &sB[bb * 512]);
      }
    }
    __syncthreads();
#pragma unroll
    for (int ks = 0; ks < 2; ++ks) {
      const int q = ks * 4 + lgrp;
      s16x8 fa[2], fb[4];
#pragma unroll
      for (int fm = 0; fm < 2; ++fm) {
        int r = m_base + fm * 16 + lrow;
        fa[fm] = *(const s16x8*)&sA[r * 64 + ((q ^ (r & 7)) * 8)];
      }
#pragma unroll
      for (int fn = 0; fn < 4; ++fn) {
        int r = n_base + fn * 16 + lrow;
        fb[fn] = *(const s16x8*)&sB[r * 64 + ((q ^ (r & 7)) * 8)];
      }
#pragma unroll
      for (int fm = 0; fm < 2; ++fm)
#pragma unroll
        for (int fn = 0; fn < 4; ++fn)
          acc[fm][fn] = __builtin_amdgcn_mfma_f32_16x16x32_bf16(fa[fm], fb[fn], acc[fm][fn], 0, 0, 0);
    }
    __syncthreads();
  }
#pragma unroll
  for (int fm = 0; fm < 2; ++fm)
#pragma unroll
    for (int fn = 0; fn < 4; ++fn)
#pragma unroll
      for (int r = 0; r < 4; ++r) {
        int row = p0 + m_base + fm * 16 + lgrp * 4 + r;
        int col = n0 + n_base + fn * 16 + lrow;
        float v = acc[fm][fn][r] + bias[col];
        if (bf16out) outB[(size_t)row * H_ + col] = f2bf(v);
        else         outF[(size_t)row * H_ + col] = v;
      }
}

// ---- max over paths ----
__global__ void pool_max(const float* __restrict__ att, float* __restrict__ pooled) {
  int j = blockIdx.x * 256 + threadIdx.x;
  float m = -3.4e38f;
  for (int p = 0; p < P_; ++p) m = fmaxf(m, att[(size_t)p * H_ + j]);
  pooled[j] = m;
}

// ---- final 1024->2 + sigmoid ----
__global__ void final_out(const float* __restrict__ pooled, const float* __restrict__ Wlin,
                          const float* __restrict__ blin, float* __restrict__ out) {
  __shared__ float r0[256], r1[256];
  int tid = threadIdx.x;
  float s0 = 0.f, s1 = 0.f;
  for (int k = tid; k < H_; k += 256) {
    float pv = pooled[k];
    s0 += pv * Wlin[k];
    s1 += pv * Wlin[H_ + k];
  }
  r0[tid] = s0; r1[tid] = s1;
  __syncthreads();
  for (int s = 128; s > 0; s >>= 1) {
    if (tid < s) { r0[tid] += r0[tid + s]; r1[tid] += r1[tid + s]; }
    __syncthreads();
  }
  if (tid == 0) {
    out[0] = sigf(r0[0] + blin[0]);
    out[1] = sigf(r1[0] + blin[1]);
  }
}

extern "C" void kernel_launch(void* const* d_in, const int* in_sizes, int n_in,
                              void* d_out, int out_size, void* d_ws, size_t ws_size,
                              hipStream_t stream) {
  const int*   paths   = (const int*)d_in[0];
  const int*   lengths = (const int*)d_in[1];
  const float* emb     = (const float*)d_in[2];
  const float* Wih     = (const float*)d_in[3];
  const float* Whh     = (const float*)d_in[4];
  const float* bih     = (const float*)d_in[5];
  const float* bhh     = (const float*)d_in[6];
  const float* Win     = (const float*)d_in[7];
  const float* bin     = (const float*)d_in[8];
  const float* Wout    = (const float*)d_in[9];
  const float* bout    = (const float*)d_in[10];
  const float* Wlin    = (const float*)d_in[11];
  const float* blin    = (const float*)d_in[12];
  float* out = (float*)d_out;

  char* ws = (char*)d_ws;
  u16*   Wc     = (u16*)  (ws);                  // 12,582,912
  u16*   X      = (u16*)  (ws + 12582912);       // 16,777,216
  u16*   h0     = (u16*)  (ws + 29360128);       //    524,288
  u16*   h1     = (u16*)  (ws + 29884416);       //    524,288
  float* Cs     = (float*)(ws + 30408704);       //  1,048,576
  float* bp     = (float*)(ws + 31457280);       //     16,384
  u16*   Wvb    = (u16*)  (ws + 31473664);       //  2,097,152
  u16*   Wob    = (u16*)  (ws + 33570816);       //  2,097,152
  float* bv     = (float*)(ws + 35667968);       //      4,096
  u16*   vb     = (u16*)  (ws + 35672064);       //    524,288
  float* att    = (float*)(ws + 36196352);       //  1,048,576
  float* pooled = (float*)(ws + 37244928);       //      4,096  (total ~37.2 MB)

  hipMemsetAsync(h0, 0, 524288, stream);
  hipMemsetAsync(Cs, 0, 1048576, stream);
  prep_wcat<<<4096, 256, 0, stream>>>(Wih, Whh, bih, bhh, Wc, bp);
  prep_wsmall<<<1024, 256, 0, stream>>>(Win, bin, Wout, Wvb, Wob, bv);
  gather_x<<<P_ * L_, 128, 0, stream>>>(paths, emb, X);

  for (int t = 0; t < L_; ++t) {
    u16* hr = (t & 1) ? h1 : h0;
    u16* hw = (t & 1) ? h0 : h1;
    lstm_step<<<dim3(32, 4), 256, 0, stream>>>(X, hr, hw, Cs, Wc, bp, lengths, t);
  }
  // after t=63 (odd) the final h sits in h0
  tail_gemm<<<dim3(8, 4), 256, 0, stream>>>(h0, Wvb, bv, vb, nullptr, 1);
  tail_gemm<<<dim3(8, 4), 256, 0, stream>>>(vb, Wob, bout, nullptr, att, 0);
  pool_max<<<4, 256, 0, stream>>>(att, pooled);
  final_out<<<1, 256, 0, stream>>>(pooled, Wlin, blin, out);
}

// Round 2
// 864.092 us; speedup vs baseline: 1.8089x; 1.8089x over previous
//
#include <hip/hip_runtime.h>
#include <stdint.h>

typedef unsigned short u16;
typedef __attribute__((ext_vector_type(8))) short s16x8;
typedef __attribute__((ext_vector_type(4))) float f32x4;

#define P_ 256
#define L_ 64
#define IDIM 512
#define H_ 1024
#define KTOT 1536

__device__ __forceinline__ u16 f2bf(float f) {
  union { float f; uint32_t u; } v; v.f = f;
  uint32_t u = v.u;
  return (u16)((u + 0x7FFFu + ((u >> 16) & 1u)) >> 16);
}
__device__ __forceinline__ float sigf(float x) { return 1.0f / (1.0f + __expf(-x)); }
__device__ __forceinline__ float tanh_fast(float x) {
  return 1.0f - 2.0f / (__expf(2.0f * x) + 1.0f);
}
__device__ __forceinline__ void async16(const u16* g, u16* l) {
  __builtin_amdgcn_global_load_lds(
      (__attribute__((address_space(1))) uint32_t*)g,
      (__attribute__((address_space(3))) uint32_t*)l, 16, 0, 0);
}

// ---- prep: W_cat bf16 [4096][1536], original row order r = g*1024 + j ----
__global__ void prep_wcat(const float* __restrict__ Wih, const float* __restrict__ Whh,
                          const float* __restrict__ bih, const float* __restrict__ bhh,
                          u16* __restrict__ Wc, float* __restrict__ bp) {
  int r = blockIdx.x;
  if (threadIdx.x == 0) bp[r] = bih[r] + bhh[r];
  const float* s1 = Wih + (size_t)r * IDIM;
  const float* s2 = Whh + (size_t)r * H_;
  u16* d = Wc + (size_t)r * KTOT;
  for (int k = threadIdx.x; k < KTOT; k += 256)
    d[k] = f2bf(k < IDIM ? s1[k] : s2[k - IDIM]);
}

// ---- prep: W_v (=W_in[2H:3H]) and W_out to bf16, b_v slice ----
__global__ void prep_wsmall(const float* __restrict__ Win, const float* __restrict__ bin,
                            const float* __restrict__ Wout,
                            u16* __restrict__ Wvb, u16* __restrict__ Wob, float* __restrict__ bv) {
  int j = blockIdx.x;
  if (threadIdx.x == 0) bv[j] = bin[2 * H_ + j];
  const float* sv = Win + (size_t)(2 * H_ + j) * H_;
  const float* so = Wout + (size_t)j * H_;
  for (int k = threadIdx.x; k < H_; k += 256) {
    Wvb[(size_t)j * H_ + k] = f2bf(sv[k]);
    Wob[(size_t)j * H_ + k] = f2bf(so[k]);
  }
}

// ---- gather embeddings -> X bf16 [t][p][i] ----
__global__ void gather_x(const int* __restrict__ paths, const float* __restrict__ emb,
                         u16* __restrict__ X) {
  int b = blockIdx.x;            // = p*64 + t (paths layout [P][L])
  int p = b >> 6, t = b & 63;
  int tok = paths[b];
  const float* src = emb + (size_t)tok * IDIM;
  u16* dst = X + ((size_t)t * P_ + p) * IDIM;
  int k = threadIdx.x * 4;
  float4 v = *(const float4*)(src + k);
  dst[k + 0] = f2bf(v.x); dst[k + 1] = f2bf(v.y);
  dst[k + 2] = f2bf(v.z); dst[k + 3] = f2bf(v.w);
}

// ---- fused LSTM step, 256 blocks (64 j-blocks x 4 p-blocks), 4 waves ----
// Block: 64 paths x 16 hidden units (x4 gates = 64 N-cols, gate-major).
// Each wave: full 64x64 tile over K-chunk of 384 (12 x k32 chunks),
// private LDS staging, no barriers in K-loop, counted-vmcnt 2-deep pipeline.
__global__ void __launch_bounds__(256)
lstm_step(const u16* __restrict__ X, const u16* __restrict__ Hprev,
          u16* __restrict__ Hnext, float* __restrict__ Cs,
          const u16* __restrict__ Wc, const float* __restrict__ bp,
          const int* __restrict__ lengths, int t) {
  __shared__ __align__(16) u16 sMem[32768];   // 64KB: 4 waves x 16KB (2 bufs x (A 4KB + B 4KB))
  const int tid = threadIdx.x;
  const int wid = tid >> 6, lane = tid & 63;
  const int lrow = lane & 15, lgrp = lane >> 4;
  const int p0 = blockIdx.y * 64;
  const int jb = blockIdx.x;                  // 0..63
  const int wr = wid * 8192;                  // wave LDS region (u16 units)

  // per-lane staging geometry: issue block = 16 rows x 64B; lane -> (row, 16B chunk)
  const int srow = lane >> 2;                 // 0..15
  const int sc   = lane & 3;
  const int csrc = sc ^ (srow & 3);           // XOR pre-swizzle on source side
  const int coff = csrc * 8;                  // u16 offset within 32-elem chunk row

  const u16* aX[4]; const u16* aH[4]; const u16* bW[4];
#pragma unroll
  for (int i = 0; i < 4; ++i) {
    int row = i * 16 + srow;
    aX[i] = X + ((size_t)t * P_ + p0 + row) * IDIM + coff;
    aH[i] = Hprev + (size_t)(p0 + row) * H_ + coff;
    bW[i] = Wc + (size_t)(i * H_ + jb * 16 + srow) * KTOT + coff;
  }

  f32x4 acc[4][4];
#pragma unroll
  for (int a = 0; a < 4; ++a)
#pragma unroll
    for (int b = 0; b < 4; ++b)
#pragma unroll
      for (int e = 0; e < 4; ++e) acc[a][b][e] = 0.0f;

  auto issue = [&](int c) {
    const int b = c & 1;
    const int k0 = wid * 384 + c * 32;        // global k of this chunk
    const bool inX = (k0 < IDIM);
    const int ka = inX ? k0 : (k0 - IDIM);
#pragma unroll
    for (int i = 0; i < 4; ++i)
      async16((inX ? aX[i] : aH[i]) + ka, &sMem[wr + b * 4096 + i * 512]);
#pragma unroll
    for (int i = 0; i < 4; ++i)
      async16(bW[i] + k0, &sMem[wr + b * 4096 + 2048 + i * 512]);
  };

  issue(0);
  issue(1);
#pragma unroll
  for (int c = 0; c < 12; ++c) {
    if (c < 11) { asm volatile("s_waitcnt vmcnt(8)" ::: "memory"); }
    else        { asm volatile("s_waitcnt vmcnt(0)" ::: "memory"); }
    __builtin_amdgcn_sched_barrier(0);
    const int b = c & 1;
    s16x8 fa[4], fb[4];
#pragma unroll
    for (int fm = 0; fm < 4; ++fm) {
      int r = fm * 16 + lrow;
      fa[fm] = *(const s16x8*)&sMem[wr + b * 4096 + r * 32 + ((lgrp ^ (r & 3)) * 8)];
    }
#pragma unroll
    for (int fn = 0; fn < 4; ++fn) {
      int r = fn * 16 + lrow;
      fb[fn] = *(const s16x8*)&sMem[wr + b * 4096 + 2048 + r * 32 + ((lgrp ^ (r & 3)) * 8)];
    }
    asm volatile("s_waitcnt lgkmcnt(0)" ::: "memory");
    __builtin_amdgcn_sched_barrier(0);
    if (c < 10) issue(c + 2);                 // overlap next-next loads with MFMA
#pragma unroll
    for (int fm = 0; fm < 4; ++fm)
#pragma unroll
      for (int fn = 0; fn < 4; ++fn)
        acc[fm][fn] = __builtin_amdgcn_mfma_f32_16x16x32_bf16(fa[fm], fb[fn], acc[fm][fn], 0, 0, 0);
  }

  // K-reduction across the 4 waves: each wave dumps acc into its own (dead)
  // staging region, then wave w reduces the fm=w row-quarter.
#pragma unroll
  for (int fm = 0; fm < 4; ++fm)
#pragma unroll
    for (int fn = 0; fn < 4; ++fn)
      *(f32x4*)&sMem[wr + (fm * 4 + fn) * 512 + lane * 8] = acc[fm][fn];
  __syncthreads();

  f32x4 red[4];
#pragma unroll
  for (int fn = 0; fn < 4; ++fn) {
    red[fn] = *(const f32x4*)&sMem[(wid * 4 + fn) * 512 + lane * 8];
#pragma unroll
    for (int src = 1; src < 4; ++src)
      red[fn] += *(const f32x4*)&sMem[src * 8192 + (wid * 4 + fn) * 512 + lane * 8];
  }

  // in-register epilogue: gate g = fn, unit j = jb*16 + lrow, row = wid*16 + lgrp*4 + r
  const int j = jb * 16 + lrow;
  const float bi = bp[j], bf = bp[H_ + j], bg = bp[2 * H_ + j], bo = bp[3 * H_ + j];
#pragma unroll
  for (int r = 0; r < 4; ++r) {
    int p = p0 + wid * 16 + lgrp * 4 + r;
    size_t off = (size_t)p * H_ + j;
    if (t < lengths[p]) {
      float gi = red[0][r] + bi, gf = red[1][r] + bf;
      float gg = red[2][r] + bg, go = red[3][r] + bo;
      float cn = sigf(gf) * Cs[off] + sigf(gi) * tanh_fast(gg);
      Cs[off] = cn;
      Hnext[off] = f2bf(sigf(go) * tanh_fast(cn));
    } else {
      Hnext[off] = Hprev[off];                // frozen: carry final h forward
    }
  }
}

// ---- tail GEMM: C[p][n] = sum_k A[p][k]*W[n][k] + bias[n] ; N=1024, K=1024 ----
__global__ void __launch_bounds__(256)
tail_gemm(const u16* __restrict__ A, const u16* __restrict__ W,
          const float* __restrict__ bias, u16* __restrict__ outB,
          float* __restrict__ outF, int bf16out) {
  __shared__ __align__(16) u16 sA[64 * 64];
  __shared__ __align__(16) u16 sB[128 * 64];
  const int tid = threadIdx.x;
  const int wid = tid >> 6, lane = tid & 63;
  const int p0 = blockIdx.y * 64;
  const int n0 = blockIdx.x * 128;
  const int m_base = (wid >> 1) * 32, n_base = (wid & 1) * 64;
  const int lrow = lane & 15, lgrp = lane >> 4;

  f32x4 acc[2][4];
#pragma unroll
  for (int a = 0; a < 2; ++a)
#pragma unroll
    for (int b = 0; b < 4; ++b)
#pragma unroll
      for (int e = 0; e < 4; ++e) acc[a][b][e] = 0.0f;

  for (int kk = 0; kk < 16; ++kk) {
    const int k0 = kk * 64;
    {
      int ab = wid * 2;
#pragma unroll
      for (int i = 0; i < 2; ++i, ++ab) {
        int row = ab * 8 + (lane >> 3);
        int cs = (lane & 7) ^ (row & 7);
        async16(A + (size_t)(p0 + row) * H_ + k0 + cs * 8, &sA[ab * 512]);
      }
    }
    {
      int bb = wid * 4;
#pragma unroll
      for (int i = 0; i < 4; ++i, ++bb) {
        int row = bb * 8 + (lane >> 3);
        int cs = (lane & 7) ^ (row & 7);
        async16(W + (size_t)(n0 + row) * H_ + k0 + cs * 8, &sB[bb * 512]);
      }
    }
    __syncthreads();
#pragma unroll
    for (int ks = 0; ks < 2; ++ks) {
      const int q = ks * 4 + lgrp;
      s16x8 fa[2], fb[4];
#pragma unroll
      for (int fm = 0; fm < 2; ++fm) {
        int r = m_base + fm * 16 + lrow;
        fa[fm] = *(const s16x8*)&sA[r * 64 + ((q ^ (r & 7)) * 8)];
      }
#pragma unroll
      for (int fn = 0; fn < 4; ++fn) {
        int r = n_base + fn * 16 + lrow;
        fb[fn] = *(const s16x8*)&sB[r * 64 + ((q ^ (r & 7)) * 8)];
      }
#pragma unroll
      for (int fm = 0; fm < 2; ++fm)
#pragma unroll
        for (int fn = 0; fn < 4; ++fn)
          acc[fm][fn] = __builtin_amdgcn_mfma_f32_16x16x32_bf16(fa[fm], fb[fn], acc[fm][fn], 0, 0, 0);
    }
    __syncthreads();
  }
#pragma unroll
  for (int fm = 0; fm < 2; ++fm)
#pragma unroll
    for (int fn = 0; fn < 4; ++fn)
#pragma unroll
      for (int r = 0; r < 4; ++r) {
        int row = p0 + m_base + fm * 16 + lgrp * 4 + r;
        int col = n0 + n_base + fn * 16 + lrow;
        float v = acc[fm][fn][r] + bias[col];
        if (bf16out) outB[(size_t)row * H_ + col] = f2bf(v);
        else         outF[(size_t)row * H_ + col] = v;
      }
}

// ---- max over paths ----
__global__ void pool_max(const float* __restrict__ att, float* __restrict__ pooled) {
  int j = blockIdx.x * 256 + threadIdx.x;
  float m = -3.4e38f;
  for (int p = 0; p < P_; ++p) m = fmaxf(m, att[(size_t)p * H_ + j]);
  pooled[j] = m;
}

// ---- final 1024->2 + sigmoid ----
__global__ void final_out(const float* __restrict__ pooled, const float* __restrict__ Wlin,
                          const float* __restrict__ blin, float* __restrict__ out) {
  __shared__ float r0[256], r1[256];
  int tid = threadIdx.x;
  float s0 = 0.f, s1 = 0.f;
  for (int k = tid; k < H_; k += 256) {
    float pv = pooled[k];
    s0 += pv * Wlin[k];
    s1 += pv * Wlin[H_ + k];
  }
  r0[tid] = s0; r1[tid] = s1;
  __syncthreads();
  for (int s = 128; s > 0; s >>= 1) {
    if (tid < s) { r0[tid] += r0[tid + s]; r1[tid] += r1[tid + s]; }
    __syncthreads();
  }
  if (tid == 0) {
    out[0] = sigf(r0[0] + blin[0]);
    out[1] = sigf(r1[0] + blin[1]);
  }
}

extern "C" void kernel_launch(void* const* d_in, const int* in_sizes, int n_in,
                              void* d_out, int out_size, void* d_ws, size_t ws_size,
                              hipStream_t stream) {
  const int*   paths   = (const int*)d_in[0];
  const int*   lengths = (const int*)d_in[1];
  const float* emb     = (const float*)d_in[2];
  const float* Wih     = (const float*)d_in[3];
  const float* Whh     = (const float*)d_in[4];
  const float* bih     = (const float*)d_in[5];
  const float* bhh     = (const float*)d_in[6];
  const float* Win     = (const float*)d_in[7];
  const float* bin     = (const float*)d_in[8];
  const float* Wout    = (const float*)d_in[9];
  const float* bout    = (const float*)d_in[10];
  const float* Wlin    = (const float*)d_in[11];
  const float* blin    = (const float*)d_in[12];
  float* out = (float*)d_out;

  char* ws = (char*)d_ws;
  u16*   Wc     = (u16*)  (ws);                  // 12,582,912
  u16*   X      = (u16*)  (ws + 12582912);       // 16,777,216
  u16*   h0     = (u16*)  (ws + 29360128);       //    524,288
  u16*   h1     = (u16*)  (ws + 29884416);       //    524,288
  float* Cs     = (float*)(ws + 30408704);       //  1,048,576
  float* bp     = (float*)(ws + 31457280);       //     16,384
  u16*   Wvb    = (u16*)  (ws + 31473664);       //  2,097,152
  u16*   Wob    = (u16*)  (ws + 33570816);       //  2,097,152
  float* bv     = (float*)(ws + 35667968);       //      4,096
  u16*   vb     = (u16*)  (ws + 35672064);       //    524,288
  float* att    = (float*)(ws + 36196352);       //  1,048,576
  float* pooled = (float*)(ws + 37244928);       //      4,096

  hipMemsetAsync(h0, 0, 524288, stream);
  hipMemsetAsync(Cs, 0, 1048576, stream);
  prep_wcat<<<4096, 256, 0, stream>>>(Wih, Whh, bih, bhh, Wc, bp);
  prep_wsmall<<<1024, 256, 0, stream>>>(Win, bin, Wout, Wvb, Wob, bv);
  gather_x<<<P_ * L_, 128, 0, stream>>>(paths, emb, X);

  for (int t = 0; t < L_; ++t) {
    u16* hr = (t & 1) ? h1 : h0;
    u16* hw = (t & 1) ? h0 : h1;
    lstm_step<<<dim3(64, 4), 256, 0, stream>>>(X, hr, hw, Cs, Wc, bp, lengths, t);
  }
  // after t=63 (odd) the final h sits in h0
  tail_gemm<<<dim3(8, 4), 256, 0, stream>>>(h0, Wvb, bv, vb, nullptr, 1);
  tail_gemm<<<dim3(8, 4), 256, 0, stream>>>(vb, Wob, bout, nullptr, att, 0);
  pool_max<<<4, 256, 0, stream>>>(att, pooled);
  final_out<<<1, 256, 0, stream>>>(pooled, Wlin, blin, out);
}

// Round 3
// 699.247 us; speedup vs baseline: 2.2354x; 1.2357x over previous
//
#include <hip/hip_runtime.h>
#include <stdint.h>

typedef unsigned short u16;
typedef unsigned int u32;
typedef __attribute__((ext_vector_type(8))) short s16x8;
typedef __attribute__((ext_vector_type(4))) float f32x4;

#define P_ 256
#define L_ 64
#define IDIM 512
#define H_ 1024

__device__ __forceinline__ u16 f2bf(float f){union{float f;u32 u;}v;v.f=f;u32 u=v.u;return (u16)((u+0x7FFFu+((u>>16)&1u))>>16);}
__device__ __forceinline__ float sigf(float x){return 1.0f/(1.0f+__expf(-x));}
__device__ __forceinline__ float tanhf_(float x){return 1.0f-2.0f/(__expf(2.0f*x)+1.0f);}

__device__ __forceinline__ s16x8 pack8v(float4 a, float4 b){
  s16x8 r;
  r[0]=(short)f2bf(a.x); r[1]=(short)f2bf(a.y); r[2]=(short)f2bf(a.z); r[3]=(short)f2bf(a.w);
  r[4]=(short)f2bf(b.x); r[5]=(short)f2bf(b.y); r[6]=(short)f2bf(b.z); r[7]=(short)f2bf(b.w);
  return r;
}
__device__ __forceinline__ s16x8 pack8(const float* s){
  return pack8v(*(const float4*)s, *(const float4*)(s+4));
}
// paired 2-lane bf16 store as one 32-bit agent-scope (device-coherent, write-through) store
__device__ __forceinline__ void st_pair(u16* addr, float hv, int lane){
  u32 b = (u32)f2bf(hv);
  u32 other = __shfl_xor(b, 1);
  if ((lane & 1) == 0) {
    u32 w = b | (other << 16);
    __hip_atomic_store((u32*)addr, w, __ATOMIC_RELAXED, __HIP_MEMORY_SCOPE_AGENT);
  }
}

#define ACQ() __builtin_amdgcn_fence(__ATOMIC_ACQUIRE, "agent")
#define REL() __builtin_amdgcn_fence(__ATOMIC_RELEASE, "agent")

// One persistent kernel for the whole network.
// 256 blocks = 4 path-groups (64 rows) x 64 unit-blocks (16 units x 4 gates).
// 4 waves/block, K-split 384 each, weights held in registers (48 s16x8/lane).
__global__ void __launch_bounds__(256, 1)
tagger_net(const int* __restrict__ paths, const int* __restrict__ lengths,
           const float* __restrict__ emb,
           const float* __restrict__ Wih, const float* __restrict__ Whh,
           const float* __restrict__ bih, const float* __restrict__ bhh,
           const float* __restrict__ Win, const float* __restrict__ bin,
           const float* __restrict__ Wout, const float* __restrict__ bout,
           const float* __restrict__ Wlin, const float* __restrict__ blin,
           u16* __restrict__ X, u16* __restrict__ h0, u16* __restrict__ h1,
           u16* __restrict__ vbuf, float* __restrict__ pmax,
           u32* flags, float* __restrict__ out)
{
  __shared__ __align__(16) float S[16384];   // 64 KB: K-reduction scratch
  const int tid  = threadIdx.x;
  const int wid  = tid >> 6, lane = tid & 63;
  const int lrow = lane & 15, lgrp = lane >> 4;
  const int bid  = blockIdx.x;
  const int g = bid >> 6, jb = bid & 63;
  const int p0 = g * 64, j0 = jb * 16;

  // ---- init phase: gather X[t=jb][p0..p0+63][:] (f32 emb -> bf16), zero own H0 chunk
  for (int it = 0; it < 16; ++it) {
    int e = (it * 256 + tid) * 8;
    int row = e >> 9, col = e & 511;
    int tok = paths[(p0 + row) * L_ + jb];
    const float* s = emb + (size_t)tok * IDIM + col;
    float4 a = *(const float4*)s, b4 = *(const float4*)(s + 4);
    *(s16x8*)(X + ((size_t)jb * P_ + p0 + row) * IDIM + col) = pack8v(a, b4);
  }
  {
    int r = tid >> 2, cg = (tid & 3) * 4;
    uint2 z; z.x = 0u; z.y = 0u;
    *(uint2*)&h0[(size_t)(p0 + r) * H_ + j0 + cg] = z;
  }
  __syncthreads();
  if (tid == 0) { REL(); atomicExch(&flags[bid], 1u); }

  // ---- load weights into registers: wave wid owns K chunks c = wid + 4*i
  s16x8 breg[12][4];
#pragma unroll
  for (int i = 0; i < 12; ++i) {
    const int k = (wid + 4 * i) * 32 + lgrp * 8;
#pragma unroll
    for (int fn = 0; fn < 4; ++fn) {
      const int n = fn * H_ + j0 + lrow;
      const float* src = (k < IDIM) ? (Wih + (size_t)n * IDIM + k)
                                    : (Whh + (size_t)n * H_ + (k - IDIM));
      breg[i][fn] = pack8(src);
    }
  }

  // per-lane epilogue state
  const int prow = p0 + wid * 16 + lgrp * 4;
  int lenr[4]; float biasv[4];
#pragma unroll
  for (int r2 = 0; r2 < 4; ++r2) lenr[r2] = lengths[prow + r2];
#pragma unroll
  for (int fn = 0; fn < 4; ++fn) {
    int n = fn * H_ + j0 + lrow;
    biasv[fn] = bih[n] + bhh[n];
  }
  float cst[4] = {0.f,0.f,0.f,0.f}, hst[4] = {0.f,0.f,0.f,0.f};

  // init barrier: group-local (X gathered per-group, H0 zeroed per-group)
  if (wid == 0) {
    for (;;) {
      u32 f = atomicAdd(&flags[p0 + lane], 0u);
      if (__all((int)(f >= 1u))) break;
      __builtin_amdgcn_s_sleep(2);
    }
    ACQ();
  }
  __syncthreads();

  const size_t aX = (size_t)(p0 + lrow) * IDIM + lgrp * 8;
  const size_t aH = (size_t)(p0 + lrow) * H_   + lgrp * 8;

  // X fragments for current step (prefetched one step ahead)
  s16x8 fx[4][4];
#define LOADX(T) do { \
    const u16* Xt_ = X + (size_t)(T) * (P_ * IDIM) + aX; \
    _Pragma("unroll") \
    for (int i_ = 0; i_ < 4; ++i_) { \
      const int k0_ = wid * 32 + i_ * 128; \
      _Pragma("unroll") \
      for (int fm_ = 0; fm_ < 4; ++fm_) \
        fx[i_][fm_] = *(const s16x8*)(Xt_ + (size_t)fm_ * (16 * IDIM) + k0_); \
    } } while (0)

  LOADX(0);

  for (int t = 0; t < L_; ++t) {
    const u16* Hr = (t & 1) ? h1 : h0;
    u16*       Hw = (t & 1) ? h0 : h1;

    f32x4 acc[4][4];
#pragma unroll
    for (int a = 0; a < 4; ++a)
#pragma unroll
      for (int b = 0; b < 4; ++b)
#pragma unroll
        for (int e = 0; e < 4; ++e) acc[a][b][e] = 0.0f;

    // ---- X phase (no dependency on other blocks) ----
#pragma unroll
    for (int i = 0; i < 4; ++i)
#pragma unroll
      for (int fm = 0; fm < 4; ++fm)
#pragma unroll
        for (int fn = 0; fn < 4; ++fn)
          acc[fm][fn] = __builtin_amdgcn_mfma_f32_16x16x32_bf16(fx[i][fm], breg[i][fn], acc[fm][fn], 0, 0, 0);

    // ---- group barrier: wait for step t-1 H of all 64 sibling blocks ----
    if (wid == 0) {
      const u32 tgt = (u32)(t + 1);
      for (;;) {
        u32 f = atomicAdd(&flags[p0 + lane], 0u);
        if (__all((int)(f >= tgt))) break;
        __builtin_amdgcn_s_sleep(2);
      }
      ACQ();                       // invalidate stale L2 lines before H loads
    }
    __syncthreads();

    // ---- H phase: 8 chunks (2 batches of 4), direct global->reg fragments ----
    const u16* Hp = Hr + aH;
#pragma unroll
    for (int half = 0; half < 2; ++half) {
      s16x8 fh[4][4];
#pragma unroll
      for (int i = 0; i < 4; ++i) {
        const int kh = wid * 32 + (half * 4 + i) * 128;
#pragma unroll
        for (int fm = 0; fm < 4; ++fm)
          fh[i][fm] = *(const s16x8*)(Hp + (size_t)fm * (16 * H_) + kh);
      }
#pragma unroll
      for (int i = 0; i < 4; ++i)
#pragma unroll
        for (int fm = 0; fm < 4; ++fm)
#pragma unroll
          for (int fn = 0; fn < 4; ++fn)
            acc[fm][fn] = __builtin_amdgcn_mfma_f32_16x16x32_bf16(fh[i][fm], breg[4 + half * 4 + i][fn], acc[fm][fn], 0, 0, 0);
    }

    // prefetch next step's X fragments (hidden under epilogue + barrier)
    const int tp1 = (t < L_ - 1) ? (t + 1) : (L_ - 1);
    LOADX(tp1);

    // ---- cross-wave K-reduction ----
#pragma unroll
    for (int fm = 0; fm < 4; ++fm)
#pragma unroll
      for (int fn = 0; fn < 4; ++fn)
        *(f32x4*)&S[((wid * 16) + fm * 4 + fn) * 256 + lane * 4] = acc[fm][fn];
    __syncthreads();
    f32x4 red[4];
#pragma unroll
    for (int fn = 0; fn < 4; ++fn) {
      red[fn] = *(const f32x4*)&S[(wid * 4 + fn) * 256 + lane * 4];
#pragma unroll
      for (int w = 1; w < 4; ++w)
        red[fn] += *(const f32x4*)&S[(w * 16 + wid * 4 + fn) * 256 + lane * 4];
    }

    // ---- in-register LSTM gate epilogue ----
#pragma unroll
    for (int r2 = 0; r2 < 4; ++r2) {
      if (t < lenr[r2]) {
        float gi = red[0][r2] + biasv[0];
        float gf = red[1][r2] + biasv[1];
        float gg = red[2][r2] + biasv[2];
        float go = red[3][r2] + biasv[3];
        float cn = sigf(gf) * cst[r2] + sigf(gi) * tanhf_(gg);
        cst[r2] = cn;
        hst[r2] = sigf(go) * tanhf_(cn);
      }
      st_pair(&Hw[(size_t)(prow + r2) * H_ + j0 + lrow], hst[r2], lane);
    }
    __syncthreads();
    if (tid == 0) atomicExch(&flags[bid], (u32)(t + 2));
  }

  // ================= tail: v = h@Wv^T+bv ; attn = v@Wout^T+bout ; maxpool ; out =================
  // final h is in h0 (t=63 wrote buffer (63+1)&1 = 0)
  if (wid == 0) {
    for (;;) {
      u32 f = atomicAdd(&flags[p0 + lane], 0u);
      if (__all((int)(f >= 65u))) break;
      __builtin_amdgcn_s_sleep(2);
    }
    ACQ();
  }
  __syncthreads();

  // ---- v GEMM: block tile 64 rows x 16 cols, wave K-split 256 ----
  {
    f32x4 acc2[4];
#pragma unroll
    for (int a = 0; a < 4; ++a)
#pragma unroll
      for (int e = 0; e < 4; ++e) acc2[a][e] = 0.0f;
    const u16* hp = h0 + aH;
    const float* wv = Win + (size_t)(2 * H_ + j0 + lrow) * H_;
#pragma unroll
    for (int ic = 0; ic < 8; ++ic) {
      const int k0 = wid * 256 + ic * 32;
      s16x8 fbv = pack8(wv + k0 + lgrp * 8);
#pragma unroll
      for (int fm = 0; fm < 4; ++fm) {
        s16x8 fav = *(const s16x8*)(hp + (size_t)fm * (16 * H_) + k0);
        acc2[fm] = __builtin_amdgcn_mfma_f32_16x16x32_bf16(fav, fbv, acc2[fm], 0, 0, 0);
      }
    }
#pragma unroll
    for (int fm = 0; fm < 4; ++fm)
      *(f32x4*)&S[(wid * 4 + fm) * 256 + lane * 4] = acc2[fm];
    __syncthreads();
    f32x4 rv = *(const f32x4*)&S[(wid) * 256 + lane * 4];
#pragma unroll
    for (int w = 1; w < 4; ++w)
      rv += *(const f32x4*)&S[(w * 4 + wid) * 256 + lane * 4];
    float bvj = bin[2 * H_ + j0 + lrow];
#pragma unroll
    for (int r2 = 0; r2 < 4; ++r2)
      st_pair(&vbuf[(size_t)(prow + r2) * H_ + j0 + lrow], rv[r2] + bvj, lane);
  }
  __syncthreads();
  if (tid == 0) atomicExch(&flags[bid], 66u);
  if (wid == 0) {
    for (;;) {
      u32 f = atomicAdd(&flags[p0 + lane], 0u);
      if (__all((int)(f >= 66u))) break;
      __builtin_amdgcn_s_sleep(2);
    }
    ACQ();
  }
  __syncthreads();

  // ---- attn GEMM + per-block max over own 64 rows ----
  {
    f32x4 acc2[4];
#pragma unroll
    for (int a = 0; a < 4; ++a)
#pragma unroll
      for (int e = 0; e < 4; ++e) acc2[a][e] = 0.0f;
    const u16* vp = vbuf + aH;
    const float* wo = Wout + (size_t)(j0 + lrow) * H_;
#pragma unroll
    for (int ic = 0; ic < 8; ++ic) {
      const int k0 = wid * 256 + ic * 32;
      s16x8 fbv = pack8(wo + k0 + lgrp * 8);
#pragma unroll
      for (int fm = 0; fm < 4; ++fm) {
        s16x8 fav = *(const s16x8*)(vp + (size_t)fm * (16 * H_) + k0);
        acc2[fm] = __builtin_amdgcn_mfma_f32_16x16x32_bf16(fav, fbv, acc2[fm], 0, 0, 0);
      }
    }
#pragma unroll
    for (int fm = 0; fm < 4; ++fm)
      *(f32x4*)&S[(wid * 4 + fm) * 256 + lane * 4] = acc2[fm];
    __syncthreads();
    f32x4 rv = *(const f32x4*)&S[(wid) * 256 + lane * 4];
#pragma unroll
    for (int w = 1; w < 4; ++w)
      rv += *(const f32x4*)&S[(w * 4 + wid) * 256 + lane * 4];
    float bo = bout[j0 + lrow];
    float m = fmaxf(fmaxf(rv[0], rv[1]), fmaxf(rv[2], rv[3])) + bo;
    __syncthreads();
    S[(wid * 4 + lgrp) * 16 + lrow] = m;
    __syncthreads();
    if (tid < 16) {
      float mx = S[tid];
#pragma unroll
      for (int s2 = 1; s2 < 16; ++s2) mx = fmaxf(mx, S[s2 * 16 + tid]);
      __hip_atomic_store(&pmax[(size_t)g * H_ + j0 + tid], mx, __ATOMIC_RELAXED, __HIP_MEMORY_SCOPE_AGENT);
    }
  }
  __syncthreads();
  if (tid == 0) atomicExch(&flags[bid], 67u);

  if (bid != 0) return;

  // ---- final: pooled max over groups, 1024->2 dot, sigmoid ----
  if (wid == 0) {
    for (;;) {
      u32 m0 = atomicAdd(&flags[lane], 0u);
      u32 m1 = atomicAdd(&flags[64 + lane], 0u);
      u32 m2 = atomicAdd(&flags[128 + lane], 0u);
      u32 m3 = atomicAdd(&flags[192 + lane], 0u);
      u32 m = min(min(m0, m1), min(m2, m3));
      if (__all((int)(m >= 67u))) break;
      __builtin_amdgcn_s_sleep(2);
    }
    ACQ();
  }
  __syncthreads();
  {
    int j4 = tid * 4;
    float s0 = 0.f, s1 = 0.f;
#pragma unroll
    for (int e = 0; e < 4; ++e) {
      float pv = pmax[j4 + e];
#pragma unroll
      for (int gg2 = 1; gg2 < 4; ++gg2) pv = fmaxf(pv, pmax[gg2 * H_ + j4 + e]);
      s0 += pv * Wlin[j4 + e];
      s1 += pv * Wlin[H_ + j4 + e];
    }
    S[tid] = s0; S[256 + tid] = s1;
    __syncthreads();
    for (int s2 = 128; s2 > 0; s2 >>= 1) {
      if (tid < s2) { S[tid] += S[tid + s2]; S[256 + tid] += S[256 + tid + s2]; }
      __syncthreads();
    }
    if (tid == 0) {
      out[0] = sigf(S[0] + blin[0]);
      out[1] = sigf(S[256] + blin[1]);
    }
  }
}

extern "C" void kernel_launch(void* const* d_in, const int* in_sizes, int n_in,
                              void* d_out, int out_size, void* d_ws, size_t ws_size,
                              hipStream_t stream) {
  const int*   paths   = (const int*)d_in[0];
  const int*   lengths = (const int*)d_in[1];
  const float* emb     = (const float*)d_in[2];
  const float* Wih     = (const float*)d_in[3];
  const float* Whh     = (const float*)d_in[4];
  const float* bih     = (const float*)d_in[5];
  const float* bhh     = (const float*)d_in[6];
  const float* Win     = (const float*)d_in[7];
  const float* bin     = (const float*)d_in[8];
  const float* Wout    = (const float*)d_in[9];
  const float* bout    = (const float*)d_in[10];
  const float* Wlin    = (const float*)d_in[11];
  const float* blin    = (const float*)d_in[12];
  float* out = (float*)d_out;

  char* ws = (char*)d_ws;
  u32*   flags  = (u32*)  (ws);                  //      1,024
  float* pmax   = (float*)(ws + 4096);           //     16,384
  u16*   X      = (u16*)  (ws + 32768);          // 16,777,216
  u16*   h0     = (u16*)  (ws + 16810240);       //    524,288  (32768+16777216 rounded to 256)
  u16*   h1     = (u16*)  (ws + 17334528);       //    524,288
  u16*   vbuf   = (u16*)  (ws + 17858816);       //    524,288  (total ~18.4 MB)

  hipMemsetAsync(flags, 0, 1024, stream);
  tagger_net<<<256, 256, 0, stream>>>(paths, lengths, emb, Wih, Whh, bih, bhh,
                                      Win, bin, Wout, bout, Wlin, blin,
                                      X, h0, h1, vbuf, pmax, flags, out);
}

// Round 4
// 630.721 us; speedup vs baseline: 2.4782x; 1.1086x over previous
//
#include <hip/hip_runtime.h>
#include <stdint.h>

typedef unsigned short u16;
typedef unsigned int u32;
typedef __attribute__((ext_vector_type(8))) short s16x8;
typedef __attribute__((ext_vector_type(4))) float f32x4;

#define P_ 256
#define L_ 64
#define IDIM 512
#define H_ 1024

__device__ __forceinline__ u16 f2bf(float f){union{float f;u32 u;}v;v.f=f;u32 u=v.u;return (u16)((u+0x7FFFu+((u>>16)&1u))>>16);}
__device__ __forceinline__ float sigf(float x){return 1.0f/(1.0f+__expf(-x));}
__device__ __forceinline__ float tanhf_(float x){return 1.0f-2.0f/(__expf(2.0f*x)+1.0f);}

__device__ __forceinline__ s16x8 pack8v(float4 a, float4 b){
  s16x8 r;
  r[0]=(short)f2bf(a.x); r[1]=(short)f2bf(a.y); r[2]=(short)f2bf(a.z); r[3]=(short)f2bf(a.w);
  r[4]=(short)f2bf(b.x); r[5]=(short)f2bf(b.y); r[6]=(short)f2bf(b.z); r[7]=(short)f2bf(b.w);
  return r;
}
__device__ __forceinline__ s16x8 pack8(const float* s){
  return pack8v(*(const float4*)s, *(const float4*)(s+4));
}
// 16B write-through store (bypasses all L2s -> coherent at IF$)
__device__ __forceinline__ void st16_coh(u16* addr, s16x8 v){
  asm volatile("global_store_dwordx4 %0, %1, off sc0 sc1" :: "v"(addr), "v"(v) : "memory");
}
// paired 2-lane bf16 -> one 32-bit write-through store
__device__ __forceinline__ void st_pair(u16* addr, float hv, int lane){
  u32 b = (u32)f2bf(hv);
  u32 other = __shfl_xor(b, 1);
  if ((lane & 1) == 0) {
    u32 w = b | (other << 16);
    __hip_atomic_store((u32*)addr, w, __ATOMIC_RELAXED, __HIP_MEMORY_SCOPE_AGENT);
  }
}
// group barrier: poll counter until >= target (relaxed agent atomic load, no cache inv)
__device__ __forceinline__ void poll_ctr(u32* ctr, u32 target, int wid, int lane){
  if (wid == 0 && lane == 0) {
    while (__hip_atomic_load(ctr, __ATOMIC_RELAXED, __HIP_MEMORY_SCOPE_AGENT) < target)
      __builtin_amdgcn_s_sleep(2);
  }
  asm volatile("" ::: "memory");
  __syncthreads();
}

// One persistent kernel. 256 blocks = 4 path-groups x 64 unit-blocks.
// H renamed per step (Hbuf[t]) -> plain cached loads, no fences/invalidations.
__global__ void __launch_bounds__(256, 1)
tagger_net(const int* __restrict__ paths, const int* __restrict__ lengths,
           const float* __restrict__ emb,
           const float* __restrict__ Wih, const float* __restrict__ Whh,
           const float* __restrict__ bih, const float* __restrict__ bhh,
           const float* __restrict__ Win, const float* __restrict__ bin,
           const float* __restrict__ Wout, const float* __restrict__ bout,
           const float* __restrict__ Wlin, const float* __restrict__ blin,
           u16* __restrict__ X, u16* __restrict__ Hbuf,
           u16* __restrict__ vbuf, float* __restrict__ pmax,
           u32* ctrs, float* __restrict__ out)
{
  __shared__ __align__(16) float S[16384];   // 64 KB K-reduction scratch
  const int tid  = threadIdx.x;
  const int wid  = tid >> 6, lane = tid & 63;
  const int lrow = lane & 15, lgrp = lane >> 4;
  const int bid  = blockIdx.x;
  const int g = bid >> 6, jb = bid & 63;
  const int p0 = g * 64, j0 = jb * 16;
  u32* ctr = ctrs + g * 64;                  // 256B-separated per-group counters

  // ---- init: gather X[t=jb][p0..p0+63][:] (write-through), zero own Hbuf[0] chunk
  for (int it = 0; it < 16; ++it) {
    int e = (it * 256 + tid) * 8;
    int row = e >> 9, col = e & 511;
    int tok = paths[(p0 + row) * L_ + jb];
    const float* s = emb + (size_t)tok * IDIM + col;
    float4 a = *(const float4*)s, b4 = *(const float4*)(s + 4);
    st16_coh(X + ((size_t)jb * P_ + p0 + row) * IDIM + col, pack8v(a, b4));
  }
#pragma unroll
  for (int i = 0; i < 2; ++i) {
    int idx = tid * 2 + i;                    // 512 u32 cells: 64 rows x 8 col-pairs
    int row = idx >> 3, cp = idx & 7;
    __hip_atomic_store((u32*)&Hbuf[(size_t)(p0 + row) * H_ + j0 + cp * 2], 0u,
                       __ATOMIC_RELAXED, __HIP_MEMORY_SCOPE_AGENT);
  }
  __syncthreads();                            // drains vmcnt
  if (tid == 0) __hip_atomic_fetch_add(ctr, 1u, __ATOMIC_RELAXED, __HIP_MEMORY_SCOPE_AGENT);

  // ---- weights into registers: wave wid owns K chunks c = wid + 4*i
  s16x8 breg[12][4];
#pragma unroll
  for (int i = 0; i < 12; ++i) {
    const int k = (wid + 4 * i) * 32 + lgrp * 8;
#pragma unroll
    for (int fn = 0; fn < 4; ++fn) {
      const int n = fn * H_ + j0 + lrow;
      const float* src = (k < IDIM) ? (Wih + (size_t)n * IDIM + k)
                                    : (Whh + (size_t)n * H_ + (k - IDIM));
      breg[i][fn] = pack8(src);
    }
  }

  const int prow = p0 + wid * 16 + lgrp * 4;
  int lenr[4]; float biasv[4];
#pragma unroll
  for (int r2 = 0; r2 < 4; ++r2) lenr[r2] = lengths[prow + r2];
#pragma unroll
  for (int fn = 0; fn < 4; ++fn) {
    int n = fn * H_ + j0 + lrow;
    biasv[fn] = bih[n] + bhh[n];
  }
  float cst[4] = {0.f,0.f,0.f,0.f}, hst[4] = {0.f,0.f,0.f,0.f};

  poll_ctr(ctr, 64u, wid, lane);              // init done (own group)

  const size_t aX = (size_t)(p0 + lrow) * IDIM + lgrp * 8;
  const size_t aH = (size_t)(p0 + lrow) * H_   + lgrp * 8;

  s16x8 fx[4][4];
#define LOADX(T) do { \
    const u16* Xt_ = X + (size_t)(T) * (P_ * IDIM) + aX; \
    _Pragma("unroll") \
    for (int i_ = 0; i_ < 4; ++i_) { \
      const int k0_ = wid * 32 + i_ * 128; \
      _Pragma("unroll") \
      for (int fm_ = 0; fm_ < 4; ++fm_) \
        fx[i_][fm_] = *(const s16x8*)(Xt_ + (size_t)fm_ * (16 * IDIM) + k0_); \
    } } while (0)

  LOADX(0);

  for (int t = 0; t < L_; ++t) {
    const u16* Hr = Hbuf + (size_t)t * (P_ * H_);
    u16*       Hw = Hbuf + (size_t)(t + 1) * (P_ * H_);

    f32x4 acc[4][4];
#pragma unroll
    for (int a = 0; a < 4; ++a)
#pragma unroll
      for (int b = 0; b < 4; ++b)
#pragma unroll
        for (int e = 0; e < 4; ++e) acc[a][b][e] = 0.0f;

    // ---- X phase (independent of other blocks) ----
#pragma unroll
    for (int i = 0; i < 4; ++i)
#pragma unroll
      for (int fm = 0; fm < 4; ++fm)
#pragma unroll
        for (int fn = 0; fn < 4; ++fn)
          acc[fm][fn] = __builtin_amdgcn_mfma_f32_16x16x32_bf16(fx[i][fm], breg[i][fn], acc[fm][fn], 0, 0, 0);

    // ---- wait for Hbuf[t] complete (64 sibling blocks) ----
    poll_ctr(ctr, 64u * (u32)(t + 1), wid, lane);

    // ---- H phase: plain cached loads (addresses never stale: write-once rename) ----
    const u16* Hp = Hr + aH;
#pragma unroll
    for (int half = 0; half < 2; ++half) {
      s16x8 fh[4][4];
#pragma unroll
      for (int i = 0; i < 4; ++i) {
        const int kh = wid * 32 + (half * 4 + i) * 128;
#pragma unroll
        for (int fm = 0; fm < 4; ++fm)
          fh[i][fm] = *(const s16x8*)(Hp + (size_t)fm * (16 * H_) + kh);
      }
#pragma unroll
      for (int i = 0; i < 4; ++i)
#pragma unroll
        for (int fm = 0; fm < 4; ++fm)
#pragma unroll
          for (int fn = 0; fn < 4; ++fn)
            acc[fm][fn] = __builtin_amdgcn_mfma_f32_16x16x32_bf16(fh[i][fm], breg[4 + half * 4 + i][fn], acc[fm][fn], 0, 0, 0);
    }

    const int tp1 = (t < L_ - 1) ? (t + 1) : (L_ - 1);
    LOADX(tp1);                               // prefetch next X under epilogue

    // ---- cross-wave K-reduction ----
#pragma unroll
    for (int fm = 0; fm < 4; ++fm)
#pragma unroll
      for (int fn = 0; fn < 4; ++fn)
        *(f32x4*)&S[((wid * 16) + fm * 4 + fn) * 256 + lane * 4] = acc[fm][fn];
    __syncthreads();
    f32x4 red[4];
#pragma unroll
    for (int fn = 0; fn < 4; ++fn) {
      red[fn] = *(const f32x4*)&S[(wid * 4 + fn) * 256 + lane * 4];
#pragma unroll
      for (int w = 1; w < 4; ++w)
        red[fn] += *(const f32x4*)&S[(w * 16 + wid * 4 + fn) * 256 + lane * 4];
    }

    // ---- in-register gate epilogue, write-through H ----
#pragma unroll
    for (int r2 = 0; r2 < 4; ++r2) {
      if (t < lenr[r2]) {
        float gi = red[0][r2] + biasv[0];
        float gf = red[1][r2] + biasv[1];
        float gg = red[2][r2] + biasv[2];
        float go = red[3][r2] + biasv[3];
        float cn = sigf(gf) * cst[r2] + sigf(gi) * tanhf_(gg);
        cst[r2] = cn;
        hst[r2] = sigf(go) * tanhf_(cn);
      }
      st_pair(&Hw[(size_t)(prow + r2) * H_ + j0 + lrow], hst[r2], lane);
    }
    __syncthreads();                          // drain stores
    if (tid == 0) __hip_atomic_fetch_add(ctr, 1u, __ATOMIC_RELAXED, __HIP_MEMORY_SCOPE_AGENT);
  }

  // ================= tail =================
  const u16* hfin = Hbuf + (size_t)L_ * (P_ * H_);
  poll_ctr(ctr, 64u * 65u, wid, lane);

  // ---- v = h@Wv^T + bv ----
  {
    f32x4 acc2[4];
#pragma unroll
    for (int a = 0; a < 4; ++a)
#pragma unroll
      for (int e = 0; e < 4; ++e) acc2[a][e] = 0.0f;
    const u16* hp = hfin + aH;
    const float* wv = Win + (size_t)(2 * H_ + j0 + lrow) * H_;
#pragma unroll
    for (int ic = 0; ic < 8; ++ic) {
      const int k0 = wid * 256 + ic * 32;
      s16x8 fbv = pack8(wv + k0 + lgrp * 8);
#pragma unroll
      for (int fm = 0; fm < 4; ++fm) {
        s16x8 fav = *(const s16x8*)(hp + (size_t)fm * (16 * H_) + k0);
        acc2[fm] = __builtin_amdgcn_mfma_f32_16x16x32_bf16(fav, fbv, acc2[fm], 0, 0, 0);
      }
    }
#pragma unroll
    for (int fm = 0; fm < 4; ++fm)
      *(f32x4*)&S[(wid * 4 + fm) * 256 + lane * 4] = acc2[fm];
    __syncthreads();
    f32x4 rv = *(const f32x4*)&S[(wid) * 256 + lane * 4];
#pragma unroll
    for (int w = 1; w < 4; ++w)
      rv += *(const f32x4*)&S[(w * 4 + wid) * 256 + lane * 4];
    float bvj = bin[2 * H_ + j0 + lrow];
#pragma unroll
    for (int r2 = 0; r2 < 4; ++r2)
      st_pair(&vbuf[(size_t)(prow + r2) * H_ + j0 + lrow], rv[r2] + bvj, lane);
  }
  __syncthreads();
  if (tid == 0) __hip_atomic_fetch_add(ctr, 1u, __ATOMIC_RELAXED, __HIP_MEMORY_SCOPE_AGENT);
  poll_ctr(ctr, 64u * 66u, wid, lane);

  // ---- attn = v@Wout^T + bout, then per-block max over own 64 rows ----
  {
    f32x4 acc2[4];
#pragma unroll
    for (int a = 0; a < 4; ++a)
#pragma unroll
      for (int e = 0; e < 4; ++e) acc2[a][e] = 0.0f;
    const u16* vp = vbuf + aH;
    const float* wo = Wout + (size_t)(j0 + lrow) * H_;
#pragma unroll
    for (int ic = 0; ic < 8; ++ic) {
      const int k0 = wid * 256 + ic * 32;
      s16x8 fbv = pack8(wo + k0 + lgrp * 8);
#pragma unroll
      for (int fm = 0; fm < 4; ++fm) {
        s16x8 fav = *(const s16x8*)(vp + (size_t)fm * (16 * H_) + k0);
        acc2[fm] = __builtin_amdgcn_mfma_f32_16x16x32_bf16(fav, fbv, acc2[fm], 0, 0, 0);
      }
    }
#pragma unroll
    for (int fm = 0; fm < 4; ++fm)
      *(f32x4*)&S[(wid * 4 + fm) * 256 + lane * 4] = acc2[fm];
    __syncthreads();
    f32x4 rv = *(const f32x4*)&S[(wid) * 256 + lane * 4];
#pragma unroll
    for (int w = 1; w < 4; ++w)
      rv += *(const f32x4*)&S[(w * 4 + wid) * 256 + lane * 4];
    float bo = bout[j0 + lrow];
    float m = fmaxf(fmaxf(rv[0], rv[1]), fmaxf(rv[2], rv[3])) + bo;
    __syncthreads();
    S[(wid * 4 + lgrp) * 16 + lrow] = m;
    __syncthreads();
    if (tid < 16) {
      float mx = S[tid];
#pragma unroll
      for (int s2 = 1; s2 < 16; ++s2) mx = fmaxf(mx, S[s2 * 16 + tid]);
      __hip_atomic_store(&pmax[(size_t)g * H_ + j0 + tid], mx, __ATOMIC_RELAXED, __HIP_MEMORY_SCOPE_AGENT);
    }
  }
  __syncthreads();
  if (tid == 0) __hip_atomic_fetch_add(ctr, 1u, __ATOMIC_RELAXED, __HIP_MEMORY_SCOPE_AGENT);

  if (bid != 0) return;

  // ---- final: max over groups, 1024->2 dot, sigmoid ----
  if (wid == 0 && lane == 0) {
    for (int g2 = 0; g2 < 4; ++g2)
      while (__hip_atomic_load(ctrs + g2 * 64, __ATOMIC_RELAXED, __HIP_MEMORY_SCOPE_AGENT) < 64u * 67u)
        __builtin_amdgcn_s_sleep(2);
  }
  asm volatile("" ::: "memory");
  __syncthreads();
  {
    int j4 = tid * 4;
    float s0 = 0.f, s1 = 0.f;
#pragma unroll
    for (int e = 0; e < 4; ++e) {
      float pv = pmax[j4 + e];
#pragma unroll
      for (int gg2 = 1; gg2 < 4; ++gg2) pv = fmaxf(pv, pmax[gg2 * H_ + j4 + e]);
      s0 += pv * Wlin[j4 + e];
      s1 += pv * Wlin[H_ + j4 + e];
    }
    S[tid] = s0; S[256 + tid] = s1;
    __syncthreads();
    for (int s2 = 128; s2 > 0; s2 >>= 1) {
      if (tid < s2) { S[tid] += S[tid + s2]; S[256 + tid] += S[256 + tid + s2]; }
      __syncthreads();
    }
    if (tid == 0) {
      out[0] = sigf(S[0] + blin[0]);
      out[1] = sigf(S[256] + blin[1]);
    }
  }
}

extern "C" void kernel_launch(void* const* d_in, const int* in_sizes, int n_in,
                              void* d_out, int out_size, void* d_ws, size_t ws_size,
                              hipStream_t stream) {
  const int*   paths   = (const int*)d_in[0];
  const int*   lengths = (const int*)d_in[1];
  const float* emb     = (const float*)d_in[2];
  const float* Wih     = (const float*)d_in[3];
  const float* Whh     = (const float*)d_in[4];
  const float* bih     = (const float*)d_in[5];
  const float* bhh     = (const float*)d_in[6];
  const float* Win     = (const float*)d_in[7];
  const float* bin     = (const float*)d_in[8];
  const float* Wout    = (const float*)d_in[9];
  const float* bout    = (const float*)d_in[10];
  const float* Wlin    = (const float*)d_in[11];
  const float* blin    = (const float*)d_in[12];
  float* out = (float*)d_out;

  char* ws = (char*)d_ws;
  u32*   ctrs   = (u32*)  (ws);                  //      1,024 (4 ctrs, 256B apart)
  float* pmax   = (float*)(ws + 4096);           //     16,384
  u16*   X      = (u16*)  (ws + 32768);          // 16,777,216
  u16*   Hbuf   = (u16*)  (ws + 16810240);       // 65 x 524,288 = 34,078,720
  u16*   vbuf   = (u16*)  (ws + 50888960);       //    524,288   (total ~51.4 MB)

  hipMemsetAsync(ctrs, 0, 1024, stream);
  tagger_net<<<256, 256, 0, stream>>>(paths, lengths, emb, Wih, Whh, bih, bhh,
                                      Win, bin, Wout, bout, Wlin, blin,
                                      X, Hbuf, vbuf, pmax, ctrs, out);
}